// Round 4
// baseline (193.972 us; speedup 1.0000x reference)
//
#include <hip/hip_runtime.h>
#include <hip/hip_cooperative_groups.h>

namespace cg = cooperative_groups;

#define IMG_H 512
#define IMG_W 512
#define NIMG 16
#define HW (IMG_H * IMG_W)        // 262,144
#define NPIX (NIMG * HW)          // 4,194,304 pixels per input
#define NTHREADS 65536            // 256 blocks x 256 threads per input
#define SEGS_PER_THREAD 4         // 262,144 segments / 65,536 threads

union Bytes { uint4 v; unsigned char b[16]; };

// ---------------------------------------------------------------------------
// Kernel 1: gray = round(((c0+c1+c2)/3)*255)  (JAX f32 op order, RNE), x4 vec.
// Block 0 also re-inits the tiny accumulator area each call.
// ---------------------------------------------------------------------------
__global__ void gray_kernel(const float4* __restrict__ og,
                            const float4* __restrict__ gg,
                            uchar4* __restrict__ gog,
                            uchar4* __restrict__ ggg,
                            unsigned int* __restrict__ vmin,
                            unsigned int* __restrict__ vmax,
                            unsigned long long* __restrict__ sum) {
    if (blockIdx.x == 0 && threadIdx.x < 8) {
        vmin[threadIdx.x] = 0xFFFFFFFFu;
        vmax[threadIdx.x] = 0u;
        sum[threadIdx.x] = 0ull;
    }
    int i = blockIdx.x * blockDim.x + threadIdx.x;   // float4-word index
    if (i >= NPIX / 4) return;
    int n = i >> 16;             // HW/4 = 65536 words per channel
    int p = i & 65535;

    const float4* o = og + (size_t)n * 3 * 65536 + p;
    float4 a = o[0], b = o[65536], c = o[2 * 65536];
    uchar4 r;
    r.x = (unsigned char)__float2int_rn(((a.x + b.x + c.x) / 3.0f) * 255.0f);
    r.y = (unsigned char)__float2int_rn(((a.y + b.y + c.y) / 3.0f) * 255.0f);
    r.z = (unsigned char)__float2int_rn(((a.z + b.z + c.z) / 3.0f) * 255.0f);
    r.w = (unsigned char)__float2int_rn(((a.w + b.w + c.w) / 3.0f) * 255.0f);
    gog[i] = r;

    const float4* g = gg + (size_t)n * 3 * 65536 + p;
    a = g[0]; b = g[65536]; c = g[2 * 65536];
    r.x = (unsigned char)__float2int_rn(((a.x + b.x + c.x) / 3.0f) * 255.0f);
    r.y = (unsigned char)__float2int_rn(((a.y + b.y + c.y) / 3.0f) * 255.0f);
    r.z = (unsigned char)__float2int_rn(((a.z + b.z + c.z) / 3.0f) * 255.0f);
    r.w = (unsigned char)__float2int_rn(((a.w + b.w + c.w) / 3.0f) * 255.0f);
    ggg[i] = r;
}

// ---------------------------------------------------------------------------
// Segment: 16 pixels of one row; rows r-1, r, r+1 (aligned 16B) + 3 boundary
// bytes at column (c0-1)&511.
// SHIFTS = (1,0),(1,1),(0,1),(-1,1); shifted[r,c] = g[(r-dx)&511,(c-dy)&511]
// ---------------------------------------------------------------------------
struct Seg {
    Bytes rm, rc, rp;
    unsigned char pm, pc, pp;
};

__device__ __forceinline__ void load_seg(const unsigned char* __restrict__ g,
                                         int sidx, Seg& s) {
    int n = sidx >> 14;                 // 16384 segments per image
    int seg = sidx & 16383;
    int r = seg >> 5;                   // 32 segments per row
    int c0 = (seg & 31) << 4;
    const unsigned char* gn = g + (n << 18);
    int rm1 = (r - 1) & 511;
    int rp1 = (r + 1) & 511;
    int cprev = (c0 - 1) & 511;
    s.rm.v = *(const uint4*)(gn + (rm1 << 9) + c0);
    s.rc.v = *(const uint4*)(gn + (r   << 9) + c0);
    s.rp.v = *(const uint4*)(gn + (rp1 << 9) + c0);
    s.pm = gn[(rm1 << 9) | cprev];
    s.pc = gn[(r   << 9) | cprev];
    s.pp = gn[(rp1 << 9) | cprev];
}

// ---------------------------------------------------------------------------
// Cooperative fused kernel: grid (256, 2), block 256.
//   Phase A: vmin/vmax of joint per (input, shift)     -> global atomics
//   grid.sync()
//   Phase B: sum of d^2 with exact f32 histc remap     -> global atomics
//   grid.sync()
//   One thread: loss = mean_a |2*S_og/2^25 - 2*S_gg/2^25|
// Segments are loaded ONCE and reused across phases (register-resident).
// ---------------------------------------------------------------------------
__global__ void fused_kernel(const unsigned char* __restrict__ g0,
                             const unsigned char* __restrict__ g1,
                             unsigned int* __restrict__ vmin,
                             unsigned int* __restrict__ vmax,
                             unsigned long long* __restrict__ sum,
                             float* __restrict__ out) {
    cg::grid_group grid = cg::this_grid();
    int inp = blockIdx.y;
    const unsigned char* g = inp ? g1 : g0;
    int t = blockIdx.x * blockDim.x + threadIdx.x;

    Seg s[SEGS_PER_THREAD];
#pragma unroll
    for (int k = 0; k < SEGS_PER_THREAD; ++k)
        load_seg(g, t + k * NTHREADS, s[k]);

    // ---- Phase A: min/max ----
    unsigned int lmin[4] = {0xFFFFFFFFu, 0xFFFFFFFFu, 0xFFFFFFFFu, 0xFFFFFFFFu};
    unsigned int lmax[4] = {0u, 0u, 0u, 0u};
#pragma unroll
    for (int k = 0; k < SEGS_PER_THREAD; ++k) {
#pragma unroll
        for (int j = 0; j < 16; ++j) {
            unsigned int base = ((unsigned int)s[k].rc.b[j]) << 8;
            unsigned int v0 = base + s[k].rm.b[j];
            unsigned int v1 = base + (j ? s[k].rm.b[j - 1] : s[k].pm);
            unsigned int v2 = base + (j ? s[k].rc.b[j - 1] : s[k].pc);
            unsigned int v3 = base + (j ? s[k].rp.b[j - 1] : s[k].pp);
            lmin[0] = min(lmin[0], v0); lmax[0] = max(lmax[0], v0);
            lmin[1] = min(lmin[1], v1); lmax[1] = max(lmax[1], v1);
            lmin[2] = min(lmin[2], v2); lmax[2] = max(lmax[2], v2);
            lmin[3] = min(lmin[3], v3); lmax[3] = max(lmax[3], v3);
        }
    }
#pragma unroll
    for (int off = 32; off > 0; off >>= 1) {
#pragma unroll
        for (int sh = 0; sh < 4; ++sh) {
            lmin[sh] = min(lmin[sh], (unsigned int)__shfl_down((int)lmin[sh], off));
            lmax[sh] = max(lmax[sh], (unsigned int)__shfl_down((int)lmax[sh], off));
        }
    }
    __shared__ unsigned int smin[4], smax[4];
    if (threadIdx.x < 4) { smin[threadIdx.x] = 0xFFFFFFFFu; smax[threadIdx.x] = 0u; }
    __syncthreads();
    if ((threadIdx.x & 63) == 0) {
#pragma unroll
        for (int sh = 0; sh < 4; ++sh) {
            atomicMin(&smin[sh], lmin[sh]);
            atomicMax(&smax[sh], lmax[sh]);
        }
    }
    __syncthreads();
    if (threadIdx.x < 4) {
        atomicMin(&vmin[inp * 4 + threadIdx.x], smin[threadIdx.x]);
        atomicMax(&vmax[inp * 4 + threadIdx.x], smax[threadIdx.x]);
    }

    grid.sync();

    // ---- Phase B: contrast sum ----
    unsigned int vm[4];
    float scale[4];
#pragma unroll
    for (int sh = 0; sh < 4; ++sh) {
        vm[sh] = vmin[inp * 4 + sh];
        scale[sh] = 65536.0f / fmaxf((float)(vmax[inp * 4 + sh] - vm[sh]), 1.0f);
    }

    unsigned int acc[4] = {0u, 0u, 0u, 0u};
#pragma unroll
    for (int k = 0; k < SEGS_PER_THREAD; ++k) {
#pragma unroll
        for (int j = 0; j < 16; ++j) {
            unsigned int base = ((unsigned int)s[k].rc.b[j]) << 8;
            unsigned int v[4];
            v[0] = base + s[k].rm.b[j];
            v[1] = base + (j ? s[k].rm.b[j - 1] : s[k].pm);
            v[2] = base + (j ? s[k].rc.b[j - 1] : s[k].pc);
            v[3] = base + (j ? s[k].rp.b[j - 1] : s[k].pp);
#pragma unroll
            for (int sh = 0; sh < 4; ++sh) {
                int b = (int)floorf((float)(v[sh] - vm[sh]) * scale[sh]);
                b = b < 0 ? 0 : (b > 65535 ? 65535 : b);
                int d = (b >> 8) - (b & 255);
                acc[sh] += (unsigned int)(d * d);
            }
        }
    }
#pragma unroll
    for (int off = 32; off > 0; off >>= 1)
#pragma unroll
        for (int sh = 0; sh < 4; ++sh)
            acc[sh] += (unsigned int)__shfl_down((int)acc[sh], off);

    __shared__ unsigned int bsum[4];
    if (threadIdx.x < 4) bsum[threadIdx.x] = 0u;
    __syncthreads();
    if ((threadIdx.x & 63) == 0)
#pragma unroll
        for (int sh = 0; sh < 4; ++sh) atomicAdd(&bsum[sh], acc[sh]);
    __syncthreads();
    if (threadIdx.x < 4)
        atomicAdd(&sum[inp * 4 + threadIdx.x], (unsigned long long)bsum[threadIdx.x]);

    grid.sync();

    // ---- loss ----
    if (blockIdx.x == 0 && blockIdx.y == 0 && threadIdx.x == 0) {
        double r = 0.0;
        for (int a = 0; a < 4; ++a) {
            double co = 2.0 * (double)sum[a]     / 33554432.0;
            double cgv = 2.0 * (double)sum[4 + a] / 33554432.0;
            r += fabs(co - cgv);
        }
        out[0] = (float)(r * 0.25);
    }
}

extern "C" void kernel_launch(void* const* d_in, const int* in_sizes, int n_in,
                              void* d_out, int out_size, void* d_ws, size_t ws_size,
                              hipStream_t stream) {
    const float* og = (const float*)d_in[0];
    const float* gg = (const float*)d_in[1];
    float* out = (float*)d_out;

    unsigned int* vmin = (unsigned int*)d_ws;
    unsigned int* vmax = vmin + 8;
    unsigned long long* sum = (unsigned long long*)((char*)d_ws + 64);
    unsigned char* gray_og = (unsigned char*)d_ws + 128;
    unsigned char* gray_gg = gray_og + NPIX;

    gray_kernel<<<(NPIX / 4) / 256, 256, 0, stream>>>(
        (const float4*)og, (const float4*)gg, (uchar4*)gray_og, (uchar4*)gray_gg,
        vmin, vmax, sum);

    void* args[] = {(void*)&gray_og, (void*)&gray_gg, (void*)&vmin,
                    (void*)&vmax, (void*)&sum, (void*)&out};
    hipLaunchCooperativeKernel((void*)fused_kernel, dim3(256, 2), dim3(256),
                               args, 0, stream);
}

// Round 5
// 41.103 us; speedup vs baseline: 4.7191x; 4.7191x over previous
//
#include <hip/hip_runtime.h>

#define HW 262144                 // 512*512
#define NPIX 4194304              // 16 images * HW, per input
#define W 512

union Bytes { uint4 v; unsigned char b[16]; };

__device__ __forceinline__ unsigned char gray1(float a, float b, float c) {
    // JAX f32 op order: ((c0+c1+c2)/3)*255, round-nearest-even
    return (unsigned char)__float2int_rn(((a + b + c) / 3.0f) * 255.0f);
}

// ---------------------------------------------------------------------------
// K1: per block = one 16-row tile of one image of one input.
//   - compute gray for rows r0-1 .. r0+16 (18 rows incl. recomputed halo) -> LDS
//   - store main 16 rows to global gray buffer
//   - compute per-block min/max of joint = center*256 + shifted for 4 shifts
//     SHIFTS = (1,0),(1,1),(0,1),(-1,1); shifted[r,c] = g[(r-dx)&511,(c-dy)&511]
//   - write 8 u32 (4 min, 4 max) to distinct slots (no atomics)
// grid (512, 2): blockIdx.x = img*32 + tile, blockIdx.y = input
// ---------------------------------------------------------------------------
__global__ __launch_bounds__(256) void k1_gray_minmax(
    const float4* __restrict__ og, const float4* __restrict__ gg,
    uchar4* __restrict__ gray, unsigned int* __restrict__ blockmm) {
    int inp = blockIdx.y;
    int img = blockIdx.x >> 5;
    int r0 = (blockIdx.x & 31) << 4;
    const float4* src = (inp ? gg : og) + (size_t)img * 3 * 65536;
    uchar4* gout = gray + (size_t)inp * (NPIX / 4) + img * 65536;

    __shared__ unsigned char lds[18 * W];
    uchar4* lds4 = (uchar4*)lds;

    // 18 rows * 128 quads = 2304 = 9 * 256
#pragma unroll
    for (int j = 0; j < 9; ++j) {
        int q = threadIdx.x + j * 256;
        int i = q >> 7;             // lds row 0..17
        int quad = q & 127;
        int ir = (r0 - 1 + i) & 511;
        float4 a = src[(size_t)ir * 128 + quad];
        float4 b = src[65536 + (size_t)ir * 128 + quad];
        float4 c = src[131072 + (size_t)ir * 128 + quad];
        uchar4 r;
        r.x = gray1(a.x, b.x, c.x);
        r.y = gray1(a.y, b.y, c.y);
        r.z = gray1(a.z, b.z, c.z);
        r.w = gray1(a.w, b.w, c.w);
        lds4[q] = r;
        if (i >= 1 && i <= 16) gout[ir * 128 + quad] = r;   // main rows only
    }
    __syncthreads();

    // each thread: 32 px of one center row
    int lr = 1 + (threadIdx.x >> 4);            // lds row 1..16
    int c0 = (threadIdx.x & 15) << 5;           // col 0..480
    const unsigned char* Lm = lds + (lr - 1) * W;
    const unsigned char* Lc = lds + lr * W;
    const unsigned char* Lp = lds + (lr + 1) * W;
    Bytes rm[2], rc[2], rp[2];
    rm[0].v = *(const uint4*)(Lm + c0); rm[1].v = *(const uint4*)(Lm + c0 + 16);
    rc[0].v = *(const uint4*)(Lc + c0); rc[1].v = *(const uint4*)(Lc + c0 + 16);
    rp[0].v = *(const uint4*)(Lp + c0); rp[1].v = *(const uint4*)(Lp + c0 + 16);
    int cp = (c0 - 1) & 511;
    unsigned char pm = Lm[cp], pc = Lc[cp], pp = Lp[cp];

    unsigned int lmin[4] = {~0u, ~0u, ~0u, ~0u};
    unsigned int lmax[4] = {0u, 0u, 0u, 0u};
#pragma unroll
    for (int h = 0; h < 2; ++h) {
#pragma unroll
        for (int j = 0; j < 16; ++j) {
            unsigned int base = ((unsigned int)rc[h].b[j]) << 8;
            unsigned int v0 = base + rm[h].b[j];
            unsigned int v1 = base + (j ? rm[h].b[j - 1] : (h ? rm[0].b[15] : pm));
            unsigned int v2 = base + (j ? rc[h].b[j - 1] : (h ? rc[0].b[15] : pc));
            unsigned int v3 = base + (j ? rp[h].b[j - 1] : (h ? rp[0].b[15] : pp));
            lmin[0] = min(lmin[0], v0); lmax[0] = max(lmax[0], v0);
            lmin[1] = min(lmin[1], v1); lmax[1] = max(lmax[1], v1);
            lmin[2] = min(lmin[2], v2); lmax[2] = max(lmax[2], v2);
            lmin[3] = min(lmin[3], v3); lmax[3] = max(lmax[3], v3);
        }
    }
#pragma unroll
    for (int off = 32; off > 0; off >>= 1) {
#pragma unroll
        for (int s = 0; s < 4; ++s) {
            lmin[s] = min(lmin[s], (unsigned int)__shfl_down((int)lmin[s], off));
            lmax[s] = max(lmax[s], (unsigned int)__shfl_down((int)lmax[s], off));
        }
    }
    __shared__ unsigned int wmin[4][4], wmax[4][4];
    int wave = threadIdx.x >> 6;
    if ((threadIdx.x & 63) == 0) {
#pragma unroll
        for (int s = 0; s < 4; ++s) { wmin[wave][s] = lmin[s]; wmax[wave][s] = lmax[s]; }
    }
    __syncthreads();
    if (threadIdx.x < 4) {
        int s = threadIdx.x;
        unsigned int mn = min(min(wmin[0][s], wmin[1][s]), min(wmin[2][s], wmin[3][s]));
        unsigned int mx = max(max(wmax[0][s], wmax[1][s]), max(wmax[2][s], wmax[3][s]));
        blockmm[inp * 4096 + s * 512 + blockIdx.x] = mn;          // mins
        blockmm[inp * 4096 + (4 + s) * 512 + blockIdx.x] = mx;    // maxes
    }
}

// ---------------------------------------------------------------------------
// K2: per block = same tile mapping.
//   - redundantly reduce this input's 512x8 block-minmax table (L2-resident)
//   - load gray tile+halo (18 rows) from global -> LDS
//   - per-pixel: b = clip(floor((joint - vmin)*scale), 0, 65535) [exact f32
//     histc emulation], d = (b>>8)-(b&255), accumulate d^2 in u32
//   - write 4 per-block partial sums to distinct slots (no atomics)
// ---------------------------------------------------------------------------
__global__ __launch_bounds__(256) void k2_contrast(
    const uchar4* __restrict__ gray, const unsigned int* __restrict__ blockmm,
    unsigned int* __restrict__ partial) {
    int inp = blockIdx.y;
    int img = blockIdx.x >> 5;
    int r0 = (blockIdx.x & 31) << 4;

    __shared__ unsigned char lds[18 * W];
    __shared__ unsigned int mmfin[8];
    uchar4* lds4 = (uchar4*)lds;
    const uchar4* gin = gray + (size_t)inp * (NPIX / 4) + img * 65536;

#pragma unroll
    for (int j = 0; j < 9; ++j) {
        int q = threadIdx.x + j * 256;
        int i = q >> 7, quad = q & 127;
        int ir = (r0 - 1 + i) & 511;
        lds4[q] = gin[ir * 128 + quad];
    }
    // reduce block-minmax table: 8 groups of 32 lanes, 16 values each
    {
        int s8 = threadIdx.x >> 5, lane = threadIdx.x & 31;
        const unsigned int* mb = blockmm + inp * 4096 + s8 * 512;
        unsigned int v = mb[lane];
#pragma unroll
        for (int k = 1; k < 16; ++k) {
            unsigned int u = mb[lane + k * 32];
            v = (s8 < 4) ? min(v, u) : max(v, u);
        }
#pragma unroll
        for (int off = 16; off > 0; off >>= 1) {
            unsigned int u = (unsigned int)__shfl_down((int)v, off, 32);
            v = (s8 < 4) ? min(v, u) : max(v, u);
        }
        if (lane == 0) mmfin[s8] = v;
    }
    __syncthreads();

    unsigned int vm[4]; float scale[4];
#pragma unroll
    for (int s = 0; s < 4; ++s) {
        vm[s] = mmfin[s];
        scale[s] = 65536.0f / fmaxf((float)(mmfin[4 + s] - vm[s]), 1.0f);
    }

    int lr = 1 + (threadIdx.x >> 4);
    int c0 = (threadIdx.x & 15) << 5;
    const unsigned char* Lm = lds + (lr - 1) * W;
    const unsigned char* Lc = lds + lr * W;
    const unsigned char* Lp = lds + (lr + 1) * W;
    Bytes rm[2], rc[2], rp[2];
    rm[0].v = *(const uint4*)(Lm + c0); rm[1].v = *(const uint4*)(Lm + c0 + 16);
    rc[0].v = *(const uint4*)(Lc + c0); rc[1].v = *(const uint4*)(Lc + c0 + 16);
    rp[0].v = *(const uint4*)(Lp + c0); rp[1].v = *(const uint4*)(Lp + c0 + 16);
    int cp = (c0 - 1) & 511;
    unsigned char pm = Lm[cp], pc = Lc[cp], pp = Lp[cp];

    unsigned int acc[4] = {0u, 0u, 0u, 0u};
#pragma unroll
    for (int h = 0; h < 2; ++h) {
#pragma unroll
        for (int j = 0; j < 16; ++j) {
            unsigned int base = ((unsigned int)rc[h].b[j]) << 8;
            unsigned int v[4];
            v[0] = base + rm[h].b[j];
            v[1] = base + (j ? rm[h].b[j - 1] : (h ? rm[0].b[15] : pm));
            v[2] = base + (j ? rc[h].b[j - 1] : (h ? rc[0].b[15] : pc));
            v[3] = base + (j ? rp[h].b[j - 1] : (h ? rp[0].b[15] : pp));
#pragma unroll
            for (int s = 0; s < 4; ++s) {
                int b = (int)floorf((float)(v[s] - vm[s]) * scale[s]);
                b = b < 0 ? 0 : (b > 65535 ? 65535 : b);
                int d = (b >> 8) - (b & 255);
                acc[s] += (unsigned int)(d * d);
            }
        }
    }
#pragma unroll
    for (int off = 32; off > 0; off >>= 1)
#pragma unroll
        for (int s = 0; s < 4; ++s)
            acc[s] += (unsigned int)__shfl_down((int)acc[s], off);

    __shared__ unsigned int wsum[4][4];
    int wave = threadIdx.x >> 6;
    if ((threadIdx.x & 63) == 0) {
#pragma unroll
        for (int s = 0; s < 4; ++s) wsum[wave][s] = acc[s];
    }
    __syncthreads();
    if (threadIdx.x < 4) {
        int s = threadIdx.x;
        unsigned int tot = wsum[0][s] + wsum[1][s] + wsum[2][s] + wsum[3][s];
        partial[(inp * 4 + s) * 512 + blockIdx.x] = tot;
    }
}

// ---------------------------------------------------------------------------
// K3: one block. Reduce 8 combos x 512 partials (exact in double < 2^53),
// loss = mean_a |2*S_og/2^25 - 2*S_gg/2^25|
// ---------------------------------------------------------------------------
__global__ __launch_bounds__(256) void k3_loss(
    const unsigned int* __restrict__ partial, float* __restrict__ out) {
    int c = threadIdx.x >> 5;       // combo = inp*4 + s
    int lane = threadIdx.x & 31;
    const unsigned int* p = partial + c * 512;
    double acc = 0.0;
#pragma unroll
    for (int k = 0; k < 16; ++k) acc += (double)p[lane + k * 32];
#pragma unroll
    for (int off = 16; off > 0; off >>= 1) acc += __shfl_down(acc, off, 32);
    __shared__ double cs[8];
    if (lane == 0) cs[c] = acc;
    __syncthreads();
    if (threadIdx.x == 0) {
        double r = 0.0;
        for (int a = 0; a < 4; ++a) {
            double co = 2.0 * cs[a]     / 33554432.0;
            double cg = 2.0 * cs[4 + a] / 33554432.0;
            r += fabs(co - cg);
        }
        out[0] = (float)(r * 0.25);
    }
}

extern "C" void kernel_launch(void* const* d_in, const int* in_sizes, int n_in,
                              void* d_out, int out_size, void* d_ws, size_t ws_size,
                              hipStream_t stream) {
    const float4* og = (const float4*)d_in[0];
    const float4* gg = (const float4*)d_in[1];
    float* out = (float*)d_out;

    // ws: blockmm u32[8192] @0 (32KB) | partial u32[4096] @32KB (16KB) | gray @64KB (8MB)
    unsigned int* blockmm = (unsigned int*)d_ws;
    unsigned int* partial = blockmm + 8192;
    uchar4* gray = (uchar4*)((char*)d_ws + 65536);

    dim3 grid(512, 2);
    k1_gray_minmax<<<grid, 256, 0, stream>>>(og, gg, gray, blockmm);
    k2_contrast<<<grid, 256, 0, stream>>>(gray, blockmm, partial);
    k3_loss<<<1, 256, 0, stream>>>(partial, out);
}